// Round 1
// baseline (127.207 us; speedup 1.0000x reference)
//
#include <hip/hip_runtime.h>

#define B_    4
#define S_    4096
#define DM    4096
#define DF    256
#define LNEPS 1e-5f

// ws layout (floats unless noted):
//   [0, B_*DF)                      feats_n   (4 KB)
//   [B_*DF, B_*DF + B_*DM)          delta     (64 KB)
//   then ints: meta[b*2+0]=applies, meta[b*2+1]=last

// Kernel 1: per-batch LayerNorm + trigger scan + last-token index.
// grid = B_, block = 256 (== DF)
__global__ void fvg_stats(const float* __restrict__ ff,
                          const int* __restrict__ token_ids,
                          const int* __restrict__ attn,
                          const float* __restrict__ gamma,
                          const float* __restrict__ beta,
                          float* __restrict__ feats_n,
                          int* __restrict__ meta) {
    const int b = blockIdx.x;
    const int t = threadIdx.x;
    __shared__ float fred[256];
    __shared__ int   ired[256];

    float v = ff[b * DF + t];

    // mean
    fred[t] = v;
    __syncthreads();
    for (int off = 128; off > 0; off >>= 1) {
        if (t < off) fred[t] += fred[t + off];
        __syncthreads();
    }
    float mu = fred[0] * (1.0f / DF);
    __syncthreads();

    // variance (two-pass)
    float d = v - mu;
    fred[t] = d * d;
    __syncthreads();
    for (int off = 128; off > 0; off >>= 1) {
        if (t < off) fred[t] += fred[t + off];
        __syncthreads();
    }
    float var  = fred[0] * (1.0f / DF);
    float rstd = rsqrtf(var + LNEPS);
    feats_n[b * DF + t] = d * rstd * gamma[t] + beta[t];

    // applies: any token == 5 or 7; last: clip(sum(mask),1)-1
    int app = 0, cnt = 0;
    for (int i = t; i < S_; i += 256) {
        int tok = token_ids[b * S_ + i];
        app |= (tok == 5) | (tok == 7);
        cnt += attn[b * S_ + i];
    }
    ired[t] = cnt;
    __syncthreads();
    for (int off = 128; off > 0; off >>= 1) {
        if (t < off) ired[t] += ired[t + off];
        __syncthreads();
    }
    int total = ired[0];
    __syncthreads();
    ired[t] = app;
    __syncthreads();
    for (int off = 128; off > 0; off >>= 1) {
        if (t < off) ired[t] |= ired[t + off];
        __syncthreads();
    }
    if (t == 0) {
        meta[b * 2 + 0] = ired[0];
        meta[b * 2 + 1] = (total < 1 ? 1 : total) - 1;
    }
}

// Kernel 2: delta[b,d] = (dot(feats_n[b,:], W[d,:]) + bias[d]) * applies[b]
// one wave (64 lanes) per (b,d); 64 lanes x float4 = 256 = DF
// grid = B_*DM/4 blocks of 256 threads (4 waves/block)
__global__ void fvg_delta(const float* __restrict__ W,
                          const float* __restrict__ bias,
                          const float* __restrict__ feats_n,
                          const int* __restrict__ meta,
                          float* __restrict__ delta) {
    int gwave = (int)((blockIdx.x * (unsigned)blockDim.x + threadIdx.x) >> 6);
    int lane  = threadIdx.x & 63;
    int b = gwave / DM;
    int d = gwave - b * DM;

    const float4* wrow = (const float4*)(W + (size_t)d * DF);
    const float4* fn   = (const float4*)(feats_n + b * DF);
    float4 w = wrow[lane];
    float4 f = fn[lane];
    float s = w.x * f.x + w.y * f.y + w.z * f.z + w.w * f.w;
    #pragma unroll
    for (int m = 32; m >= 1; m >>= 1) s += __shfl_xor(s, m, 64);

    if (lane == 0) {
        float a = (float)meta[b * 2 + 0];
        delta[b * DM + d] = (s + bias[d]) * a;  // STRENGTH == 1.0
    }
}

// Kernel 3: bulk copy x -> out, float4 grid-stride
__global__ void fvg_copy(const float4* __restrict__ x,
                         float4* __restrict__ out, long n4) {
    long i      = (long)blockIdx.x * blockDim.x + threadIdx.x;
    long stride = (long)gridDim.x * blockDim.x;
    for (; i < n4; i += stride) out[i] = x[i];
}

// Kernel 4: out[b, last[b], :] += delta[b, :]
// grid = B_*DM/256 blocks of 256
__global__ void fvg_add(float* __restrict__ out,
                        const float* __restrict__ delta,
                        const int* __restrict__ meta) {
    int i = blockIdx.x * blockDim.x + threadIdx.x;  // [0, B_*DM)
    int b = i >> 12;          // / DM
    int d = i & (DM - 1);     // % DM
    int last = meta[b * 2 + 1];
    size_t off = ((size_t)b * S_ + (size_t)last) * DM + d;
    out[off] += delta[i];
}

extern "C" void kernel_launch(void* const* d_in, const int* in_sizes, int n_in,
                              void* d_out, int out_size, void* d_ws, size_t ws_size,
                              hipStream_t stream) {
    const float* x     = (const float*)d_in[0];
    const float* ff    = (const float*)d_in[1];
    const int*   toks  = (const int*)d_in[2];
    const int*   attn  = (const int*)d_in[3];
    const float* gamma = (const float*)d_in[4];
    const float* beta  = (const float*)d_in[5];
    const float* W     = (const float*)d_in[6];
    const float* bias  = (const float*)d_in[7];
    float* out = (float*)d_out;

    float* feats_n = (float*)d_ws;
    float* delta   = feats_n + B_ * DF;
    int*   meta    = (int*)(delta + B_ * DM);

    // 1. stats
    fvg_stats<<<B_, 256, 0, stream>>>(ff, toks, attn, gamma, beta, feats_n, meta);

    // 2. delta: B_*DM waves, 4 waves/block -> B_*DM/4 blocks
    fvg_delta<<<(B_ * DM) / 4, 256, 0, stream>>>(W, bias, feats_n, meta, delta);

    // 3. copy: 64M floats = 16M float4
    long n4 = (long)out_size / 4;
    int copy_blocks = 2048;
    fvg_copy<<<copy_blocks, 256, 0, stream>>>((const float4*)x, (float4*)out, n4);

    // 4. scatter-add
    fvg_add<<<(B_ * DM) / 256, 256, 0, stream>>>(out, delta, meta);
}